// Round 5
// baseline (294.353 us; speedup 1.0000x reference)
//
#include <hip/hip_runtime.h>

// Problem constants
#define BB 32
#define LL 256
#define NN 1024
#define BL 8192         // B*L
#define TOPK 307        // int(1024*0.3)
#define SPLITK 28

typedef unsigned short ushort_t;
typedef unsigned long long u64;
typedef __bf16 bf16x8 __attribute__((ext_vector_type(8)));
typedef float f32x4 __attribute__((ext_vector_type(4)));

// round-to-nearest-even float -> bf16
__device__ __forceinline__ ushort_t f2bf(float f) {
    unsigned int u = __float_as_uint(f);
    u += 0x7FFFu + ((u >> 16) & 1u);
    return (ushort_t)(u >> 16);
}
__device__ __forceinline__ float bf2f(ushort_t h) {
    return __uint_as_float(((unsigned int)h) << 16);
}

// async global->LDS DMA, 16B/lane; LDS dest = wave-uniform base + lane*16
__device__ __forceinline__ void gload16(const void* g, const void* l) {
    __builtin_amdgcn_global_load_lds(
        (__attribute__((address_space(1))) void*)(unsigned long long)g,
        (__attribute__((address_space(3))) void*)(unsigned int)(unsigned long long)l,
        16, 0, 0);
}

// ---------------------------------------------------------------------------
// K1: inv_norm[b*N + n] = 1 / max(||x[b,:,n]||, 1e-12)
__global__ __launch_bounds__(256) void k_norms(const float* __restrict__ x,
                                               float* __restrict__ invn) {
    int g = blockIdx.x * 256 + threadIdx.x;   // g = b*N + n
    int b = g >> 10, n = g & (NN - 1);
    const float* p = x + (size_t)b * LL * NN + n;
    float s = 0.f;
#pragma unroll 8
    for (int l = 0; l < LL; ++l) {
        float v = p[(size_t)l * NN];
        s = fmaf(v, v, s);
    }
    invn[g] = 1.0f / fmaxf(sqrtf(s), 1e-12f);
}

// ---------------------------------------------------------------------------
// K2: transpose x [8192][1024] -> node-major bf16: xhi/xlo (normalized split), xbf (raw)
__global__ __launch_bounds__(256) void k_transpose_x(const float* __restrict__ x,
                                                     const float* __restrict__ invn,
                                                     ushort_t* __restrict__ xhi,
                                                     ushort_t* __restrict__ xlo,
                                                     ushort_t* __restrict__ xbf) {
    __shared__ float tile[32][33];
    int c0 = blockIdx.x * 32;       // node dim
    int r0 = blockIdx.y * 32;       // b*L dim
    int tx = threadIdx.x, ty = threadIdx.y;   // (32,8)
#pragma unroll
    for (int j = 0; j < 32; j += 8)
        tile[ty + j][tx] = x[(size_t)(r0 + ty + j) * NN + c0 + tx];
    __syncthreads();
    int b = r0 >> 8;                // whole tile in same batch (32 | 256)
#pragma unroll
    for (int j = 0; j < 32; j += 8) {
        int n = c0 + ty + j;
        size_t o = (size_t)n * BL + r0 + tx;
        float v = tile[tx][ty + j];
        xbf[o] = f2bf(v);
        float s = v * invn[b * NN + n];
        ushort_t hi = f2bf(s);
        xhi[o] = hi;
        xlo[o] = f2bf(s - bf2f(hi));
    }
}

// ---------------------------------------------------------------------------
// GEMM1: sim += (1/B) Xs.Xs^T, split-bf16 (hi*hi + hi*lo + lo*hi), MFMA.
// Upper-tri 128-tiles, splitK=28 (1008 blocks), single 32KB LDS buffer,
// 4 blocks/CU: cross-block overlap hides the per-iter DMA drain.
__global__ __launch_bounds__(256, 4) void k_sim_mfma(const ushort_t* __restrict__ Xhi,
                                                     const ushort_t* __restrict__ Xlo,
                                                     float* __restrict__ sim) {
    __shared__ ushort_t sAh[4096], sAl[4096];
    __shared__ ushort_t sBh[4096], sBl[4096];
    const int t = threadIdx.x, l = t & 63, w = t >> 6;
    int id = blockIdx.x, ti = 0;               // [0,36) -> upper-tri (ti,tj)
    while (id >= 8 - ti) { id -= 8 - ti; ++ti; }
    const int tj = ti + id;
    const int i0 = ti * 128, j0 = tj * 128;
    const int z = blockIdx.y;
    const int it0 = (256 * z) / SPLITK, it1 = (256 * (z + 1)) / SPLITK;
    const int ra = t >> 2, qa = (t & 3) * 8;           // chunk t
    const int rb = ra + 64;                            // chunk t+256 (same quad)
    const int lb0 = 512 * w, lb1 = 512 * (w + 4);      // wave-uniform LDS bases
    const int wr = (w >> 1) * 64, wc = (w & 1) * 64;
    const int lrow = l & 15, lq = (l >> 4) * 8;
    const ushort_t* Ah = Xhi + (size_t)i0 * BL;
    const ushort_t* Al = Xlo + (size_t)i0 * BL;
    const ushort_t* Bh = Xhi + (size_t)j0 * BL;
    const ushort_t* Bl = Xlo + (size_t)j0 * BL;

    f32x4 acc[4][4] = {};
    for (int it = it0; it < it1; ++it) {
        const int k0 = it * 32;
        __syncthreads();   // prior iter's LDS reads done
        gload16(Ah + (size_t)ra * BL + k0 + qa, sAh + lb0);
        gload16(Ah + (size_t)rb * BL + k0 + qa, sAh + lb1);
        gload16(Al + (size_t)ra * BL + k0 + qa, sAl + lb0);
        gload16(Al + (size_t)rb * BL + k0 + qa, sAl + lb1);
        gload16(Bh + (size_t)ra * BL + k0 + qa, sBh + lb0);
        gload16(Bh + (size_t)rb * BL + k0 + qa, sBh + lb1);
        gload16(Bl + (size_t)ra * BL + k0 + qa, sBl + lb0);
        gload16(Bl + (size_t)rb * BL + k0 + qa, sBl + lb1);
        __syncthreads();   // DMA drained
        bf16x8 ah[4], al[4], bh[4], bl[4];
#pragma unroll
        for (int r = 0; r < 4; ++r) {
            ah[r] = *(const bf16x8*)&sAh[(wr + r * 16 + lrow) * 32 + lq];
            al[r] = *(const bf16x8*)&sAl[(wr + r * 16 + lrow) * 32 + lq];
        }
#pragma unroll
        for (int c = 0; c < 4; ++c) {
            bh[c] = *(const bf16x8*)&sBh[(wc + c * 16 + lrow) * 32 + lq];
            bl[c] = *(const bf16x8*)&sBl[(wc + c * 16 + lrow) * 32 + lq];
        }
#pragma unroll
        for (int r = 0; r < 4; ++r)
#pragma unroll
            for (int c = 0; c < 4; ++c) {
                acc[r][c] = __builtin_amdgcn_mfma_f32_16x16x32_bf16(ah[r], bh[c], acc[r][c], 0, 0, 0);
                acc[r][c] = __builtin_amdgcn_mfma_f32_16x16x32_bf16(ah[r], bl[c], acc[r][c], 0, 0, 0);
                acc[r][c] = __builtin_amdgcn_mfma_f32_16x16x32_bf16(al[r], bh[c], acc[r][c], 0, 0, 0);
            }
    }
    const int orow = i0 + wr + (l >> 4) * 4;
    const int ocol = j0 + wc + lrow;
#pragma unroll
    for (int r = 0; r < 4; ++r)
#pragma unroll
        for (int c = 0; c < 4; ++c)
#pragma unroll
            for (int p = 0; p < 4; ++p)
                atomicAdd(&sim[(size_t)(orow + r * 16 + p) * NN + ocol + c * 16],
                          acc[r][c][p] * (1.0f / BB));
}

// ---------------------------------------------------------------------------
// Mirror strictly-lower 128-tiles from upper: sim[i][j] = sim[j][i]
__global__ __launch_bounds__(256) void k_mirror(float* __restrict__ sim) {
    __shared__ float tile[32][33];
    int c0 = blockIdx.x * 32;   // output col (j)
    int r0 = blockIdx.y * 32;   // output row (i)
    if ((r0 >> 7) <= (c0 >> 7)) return;
    int tx = threadIdx.x, ty = threadIdx.y;
#pragma unroll
    for (int j = 0; j < 32; j += 8)
        tile[ty + j][tx] = sim[(size_t)(c0 + ty + j) * NN + r0 + tx];
    __syncthreads();
#pragma unroll
    for (int j = 0; j < 32; j += 8)
        sim[(size_t)(r0 + ty + j) * NN + c0 + tx] = tile[tx][ty + j];
}

// ---------------------------------------------------------------------------
// K3: exact top-307 per row (excl self), one wave/row, ballot binary search.
// Fused: atomicAdd kept weights into deg[dst] (deg pre-zeroed).
__global__ __launch_bounds__(256) void k_topk(const float* __restrict__ sim,
                                              float* __restrict__ A,
                                              float* __restrict__ deg) {
    const int t = threadIdx.x, l = t & 63, w = t >> 6;
    const int n = blockIdx.x * 4 + w;
    const float* row = sim + (size_t)n * NN;
    float v[16]; unsigned key[16];
#pragma unroll
    for (int j = 0; j < 16; ++j) {
        int m = j * 64 + l;
        float f = row[m];
        v[j] = f;
        unsigned u = __float_as_uint(f);
        unsigned kk = (u & 0x80000000u) ? ~u : (u | 0x80000000u);
        key[j] = (m == n) ? 0u : kk;   // self excluded (self-sim is row max)
    }
    unsigned cur = 0u;
    for (int bit = 31; bit >= 0; --bit) {
        unsigned cand = cur | (1u << bit);
        int c = 0;
#pragma unroll
        for (int j = 0; j < 16; ++j)
            c += __popcll(__ballot(key[j] >= cand));
        if (c >= TOPK) cur = cand;
    }
    const unsigned T = cur;
    int cgt = 0; u64 eq[16];
#pragma unroll
    for (int j = 0; j < 16; ++j) {
        cgt += __popcll(__ballot(key[j] > T));
        eq[j] = __ballot(key[j] == T);
    }
    const int need = TOPK - cgt;
    const u64 mymask = (l == 0) ? 0ull : (~0ull >> (64 - l));
    int base = 0;
#pragma unroll
    for (int j = 0; j < 16; ++j) {
        int rank = base + __popcll(eq[j] & mymask);
        bool keep = (key[j] > T) | ((key[j] == T) & (rank < need));
        float av = keep ? v[j] : 0.0f;
        A[(size_t)n * NN + j * 64 + l] = av;
        if (keep) atomicAdd(&deg[j * 64 + l], av);
        base += __popcll(eq[j]);
    }
}

// ---------------------------------------------------------------------------
// K4: dinv = deg>0 ? 1/sqrt(deg) : 0
__global__ __launch_bounds__(256) void k_dinv(const float* __restrict__ deg,
                                              float* __restrict__ dinv) {
    int d = blockIdx.x * 256 + threadIdx.x;
    float s = deg[d];
    dinv[d] = (s > 0.f) ? (1.0f / sqrtf(s)) : 0.0f;
}

// ---------------------------------------------------------------------------
// K5: Atr[d][s] = bf16( A[s][d] * dinv[d] * dinv[s] )
__global__ __launch_bounds__(256) void k_prescale_tr(const float* __restrict__ A,
                                                     const float* __restrict__ dinv,
                                                     ushort_t* __restrict__ Atr) {
    __shared__ float tile[32][33];
    int c0 = blockIdx.x * 32;   // d
    int r0 = blockIdx.y * 32;   // s
    int tx = threadIdx.x, ty = threadIdx.y;
#pragma unroll
    for (int j = 0; j < 32; j += 8)
        tile[ty + j][tx] = A[(size_t)(r0 + ty + j) * NN + c0 + tx];
    __syncthreads();
#pragma unroll
    for (int j = 0; j < 32; j += 8) {
        int d = c0 + ty + j;
        int s = r0 + tx;
        Atr[(size_t)d * NN + s] = f2bf(tile[tx][ty + j] * dinv[d] * dinv[s]);
    }
}

// ---------------------------------------------------------------------------
// K5b: WT[o][l] = bf16( W[l][o] )
__global__ __launch_bounds__(256) void k_wt(const float* __restrict__ W,
                                            ushort_t* __restrict__ WT) {
    __shared__ float tile[32][33];
    int c0 = blockIdx.x * 32;   // o
    int r0 = blockIdx.y * 32;   // l
    int tx = threadIdx.x, ty = threadIdx.y;
#pragma unroll
    for (int j = 0; j < 32; j += 8)
        tile[ty + j][tx] = W[(size_t)(r0 + ty + j) * LL + c0 + tx];
    __syncthreads();
#pragma unroll
    for (int j = 0; j < 32; j += 8)
        WT[(size_t)(c0 + ty + j) * LL + r0 + tx] = f2bf(tile[tx][ty + j]);
}

// ---------------------------------------------------------------------------
// Generic bf16 NT MFMA GEMM: C[i][j] = sum_k A[i][k]*B[j][k] (+bias for fp32).
// 128x128 tile, BK=32, 2x2 waves acc[4][4], LDS double-buffer (32KB) +
// global_load_lds, batched via blockIdx.z.
__global__ __launch_bounds__(256, 4) void k_mfma_nt(const ushort_t* __restrict__ A,
                                                    const ushort_t* __restrict__ B,
                                                    void* __restrict__ Cv,
                                                    const float* __restrict__ bias,
                                                    int lda, int ldb, int ldc,
                                                    long strA, long strB, long strC,
                                                    int K, int bf16out) {
    __shared__ ushort_t sA[2][4096], sB[2][4096];
    const int t = threadIdx.x, l = t & 63, w = t >> 6;
    const int i0 = blockIdx.y * 128, j0 = blockIdx.x * 128, z = blockIdx.z;
    const ushort_t* Ab = A + (size_t)z * strA;
    const ushort_t* Bb = B + (size_t)z * strB;
    const int ra = t >> 2, qa = (t & 3) * 8;
    const int rb = ra + 64;
    const int lb0 = 512 * w, lb1 = 512 * (w + 4);
    const int wr = (w >> 1) * 64, wc = (w & 1) * 64;
    const int lrow = l & 15, lq = (l >> 4) * 8;

    auto dma = [&](int k0, int buf) {
        gload16(Ab + (size_t)(i0 + ra) * lda + k0 + qa, &sA[buf][lb0]);
        gload16(Ab + (size_t)(i0 + rb) * lda + k0 + qa, &sA[buf][lb1]);
        gload16(Bb + (size_t)(j0 + ra) * ldb + k0 + qa, &sB[buf][lb0]);
        gload16(Bb + (size_t)(j0 + rb) * ldb + k0 + qa, &sB[buf][lb1]);
    };

    f32x4 acc[4][4] = {};
    dma(0, 0);
    for (int k0 = 0; k0 < K; k0 += 32) {
        const int cur = (k0 >> 5) & 1;
        __syncthreads();                        // drains DMA into buf[cur]
        if (k0 + 32 < K) dma(k0 + 32, cur ^ 1); // prefetch next into other buf
        bf16x8 af[4], bf_[4];
#pragma unroll
        for (int r = 0; r < 4; ++r)
            af[r] = *(const bf16x8*)&sA[cur][(wr + r * 16 + lrow) * 32 + lq];
#pragma unroll
        for (int c = 0; c < 4; ++c)
            bf_[c] = *(const bf16x8*)&sB[cur][(wc + c * 16 + lrow) * 32 + lq];
#pragma unroll
        for (int r = 0; r < 4; ++r)
#pragma unroll
            for (int c = 0; c < 4; ++c)
                acc[r][c] = __builtin_amdgcn_mfma_f32_16x16x32_bf16(af[r], bf_[c], acc[r][c], 0, 0, 0);
    }
    const int orow = i0 + wr + (l >> 4) * 4;
    const int ocol = j0 + wc + lrow;
    if (bf16out) {
        ushort_t* Cp = (ushort_t*)Cv + (size_t)z * strC;
#pragma unroll
        for (int r = 0; r < 4; ++r)
#pragma unroll
            for (int c = 0; c < 4; ++c)
#pragma unroll
                for (int p = 0; p < 4; ++p)
                    Cp[(size_t)(orow + r * 16 + p) * ldc + ocol + c * 16] = f2bf(acc[r][c][p]);
    } else {
        float* Cp = (float*)Cv + (size_t)z * strC;
#pragma unroll
        for (int r = 0; r < 4; ++r)
#pragma unroll
            for (int c = 0; c < 4; ++c)
#pragma unroll
                for (int p = 0; p < 4; ++p) {
                    float bv = bias ? bias[(orow + r * 16 + p) & (LL - 1)] : 0.0f;
                    Cp[(size_t)(orow + r * 16 + p) * ldc + ocol + c * 16] = acc[r][c][p] + bv;
                }
    }
}

// ---------------------------------------------------------------------------
extern "C" void kernel_launch(void* const* d_in, const int* in_sizes, int n_in,
                              void* d_out, int out_size, void* d_ws, size_t ws_size,
                              hipStream_t stream) {
    const float* x      = (const float*)d_in[0];   // [B, L, N]
    const float* weight = (const float*)d_in[1];   // [L, L]
    const float* bias   = (const float*)d_in[2];   // [L]
    float* out = (float*)d_out;                    // [B, L, N] == [bl][d]

    char* p = (char*)d_ws;
    ushort_t* xhi  = (ushort_t*)p; p += (size_t)NN * BL * 2;   // 16MB
    ushort_t* xlo  = (ushort_t*)p; p += (size_t)NN * BL * 2;   // 16MB
    ushort_t* xbf  = (ushort_t*)p; p += (size_t)NN * BL * 2;   // 16MB
    ushort_t* xwT  = (ushort_t*)p; p += (size_t)BL * NN * 2;   // 16MB [bl][n]
    ushort_t* Atrb = (ushort_t*)p; p += (size_t)NN * NN * 2;   // 2MB
    ushort_t* WTb  = (ushort_t*)p; p += (size_t)LL * LL * 2;   // 128KB
    float* sim  = (float*)p; p += (size_t)NN * NN * 4;         // 4MB
    float* Aw   = (float*)p; p += (size_t)NN * NN * 4;         // 4MB
    float* deg  = (float*)p; p += NN * 4;
    float* dinv = (float*)p; p += NN * 4;
    float* invn = (float*)p; p += (size_t)BB * NN * 4;         // 128KB

    // 1. per-(n,b) inverse norms
    k_norms<<<dim3(BB * NN / 256), 256, 0, stream>>>(x, invn);
    // 2. transpose to node-major bf16 (hi/lo normalized + raw)
    k_transpose_x<<<dim3(NN / 32, BL / 32), dim3(32, 8), 0, stream>>>(x, invn, xhi, xlo, xbf);
    // 3. sim upper-tri (split-bf16 MFMA, splitK=28, 4 blocks/CU), then mirror
    hipMemsetAsync(sim, 0, (size_t)NN * NN * 4, stream);
    hipMemsetAsync(deg, 0, NN * 4, stream);
    k_sim_mfma<<<dim3(36, SPLITK), 256, 0, stream>>>(xhi, xlo, sim);
    k_mirror<<<dim3(NN / 32, NN / 32), dim3(32, 8), 0, stream>>>(sim);
    // 4. exact top-307 per row -> Aw, fused deg accumulation
    k_topk<<<dim3(NN / 4), 256, 0, stream>>>(sim, Aw, deg);
    // 5. rsqrt
    k_dinv<<<dim3(NN / 256), 256, 0, stream>>>(deg, dinv);
    // 6. Atr = bf16(D^-1/2 A^T D^-1/2), WT = bf16(W^T)
    k_prescale_tr<<<dim3(NN / 32, NN / 32), dim3(32, 8), 0, stream>>>(Aw, dinv, Atrb);
    k_wt<<<dim3(LL / 32, LL / 32), dim3(32, 8), 0, stream>>>(weight, WTb);
    // 7. xwT[b*256+o][n] = sum_l WT[o][l] * xbf[n][b*256+l]  (batched NT, bf16 out)
    k_mfma_nt<<<dim3(NN / 128, LL / 128, BB), 256, 0, stream>>>(
        WTb, xbf, xwT, nullptr, LL, BL, NN, 0, LL, (long)LL * NN, LL, 1);
    // 8. out[bl][d] = sum_s xwT[bl][s] * Atr[d][s] + bias[bl&255]  (NT, fused epilogue)
    k_mfma_nt<<<dim3(NN / 128, BL / 128, 1), 256, 0, stream>>>(
        xwT, Atrb, out, bias, NN, NN, NN, 0, 0, 0, NN, 0);
}

// Round 6
// 249.843 us; speedup vs baseline: 1.1782x; 1.1782x over previous
//
#include <hip/hip_runtime.h>

// Problem constants
#define BB 32
#define LL 256
#define NN 1024
#define BL 8192         // B*L
#define TOPK 307        // int(1024*0.3)
#define SPLITK 16
#define NTILES 36       // upper-tri 128x128 tiles of 1024x1024
#define PART_STRIDE ((size_t)NTILES * 16384)

typedef unsigned short ushort_t;
typedef unsigned long long u64;
typedef __bf16 bf16x8 __attribute__((ext_vector_type(8)));
typedef float f32x4 __attribute__((ext_vector_type(4)));

// round-to-nearest-even float -> bf16
__device__ __forceinline__ ushort_t f2bf(float f) {
    unsigned int u = __float_as_uint(f);
    u += 0x7FFFu + ((u >> 16) & 1u);
    return (ushort_t)(u >> 16);
}
__device__ __forceinline__ float bf2f(ushort_t h) {
    return __uint_as_float(((unsigned int)h) << 16);
}

// async global->LDS DMA, 16B/lane; LDS dest = wave-uniform base + lane*16
__device__ __forceinline__ void gload16(const void* g, const void* l) {
    __builtin_amdgcn_global_load_lds(
        (__attribute__((address_space(1))) void*)(unsigned long long)g,
        (__attribute__((address_space(3))) void*)(unsigned int)(unsigned long long)l,
        16, 0, 0);
}

// ---------------------------------------------------------------------------
// K1 (fused norms + transpose): one pass over x.
// Block = (32,8), grid = (N/32, B). Stages a [256 l][32 n] fp32 tile, computes
// per-n inv-norm in LDS, emits node-major bf16 xhi/xlo (normalized split) and
// xbf (raw).
__global__ __launch_bounds__(256) void k_prep(const float* __restrict__ x,
                                              ushort_t* __restrict__ xhi,
                                              ushort_t* __restrict__ xlo,
                                              ushort_t* __restrict__ xbf) {
    __shared__ float tile[LL][33];
    __shared__ float red[8][33];
    __shared__ float inv[32];
    const int tx = threadIdx.x, ty = threadIdx.y;
    const int n0 = blockIdx.x * 32, b = blockIdx.y;
    const float* xb = x + (size_t)b * LL * NN + n0;
    float s = 0.f;
#pragma unroll
    for (int j = 0; j < 32; ++j) {
        int l = j * 8 + ty;
        float v = xb[(size_t)l * NN + tx];
        tile[l][tx] = v;
        s = fmaf(v, v, s);
    }
    red[ty][tx] = s;
    __syncthreads();
    if (ty == 0) {
        float acc = 0.f;
#pragma unroll
        for (int j = 0; j < 8; ++j) acc += red[j][tx];
        inv[tx] = 1.0f / fmaxf(sqrtf(acc), 1e-12f);
    }
    __syncthreads();
    const int tid = ty * 32 + tx;   // == l for the write phase
#pragma unroll
    for (int nl = 0; nl < 32; ++nl) {
        float v = tile[tid][nl];
        size_t o = (size_t)(n0 + nl) * BL + b * LL + tid;
        xbf[o] = f2bf(v);
        float sc = v * inv[nl];
        ushort_t hi = f2bf(sc);
        xhi[o] = hi;
        xlo[o] = f2bf(sc - bf2f(hi));
    }
}

// ---------------------------------------------------------------------------
// GEMM1: partial sims, split-bf16 (hi*hi + hi*lo + lo*hi), MFMA.
// Upper-tri 128-tiles, splitK=16, NO atomics: each (tile,z) block writes a
// compact fp32 128x128 partial to part[z][tile].
__global__ __launch_bounds__(256, 4) void k_sim_mfma(const ushort_t* __restrict__ Xhi,
                                                     const ushort_t* __restrict__ Xlo,
                                                     float* __restrict__ part) {
    __shared__ ushort_t sAh[4096], sAl[4096];
    __shared__ ushort_t sBh[4096], sBl[4096];
    const int t = threadIdx.x, l = t & 63, w = t >> 6;
    int id = blockIdx.x, ti = 0;               // [0,36) -> upper-tri (ti,tj)
    while (id >= 8 - ti) { id -= 8 - ti; ++ti; }
    const int tj = ti + id;
    const int i0 = ti * 128, j0 = tj * 128;
    const int z = blockIdx.y;
    const int it0 = 16 * z, it1 = it0 + 16;    // 256/SPLITK = 16 iters each
    const int ra = t >> 2, qa = (t & 3) * 8;
    const int rb = ra + 64;
    const int lb0 = 512 * w, lb1 = 512 * (w + 4);
    const int wr = (w >> 1) * 64, wc = (w & 1) * 64;
    const int lrow = l & 15, lq = (l >> 4) * 8;
    const ushort_t* Ah = Xhi + (size_t)i0 * BL;
    const ushort_t* Al = Xlo + (size_t)i0 * BL;
    const ushort_t* Bh = Xhi + (size_t)j0 * BL;
    const ushort_t* Bl = Xlo + (size_t)j0 * BL;

    f32x4 acc[4][4] = {};
    for (int it = it0; it < it1; ++it) {
        const int k0 = it * 32;
        __syncthreads();   // prior iter's LDS reads done
        gload16(Ah + (size_t)ra * BL + k0 + qa, sAh + lb0);
        gload16(Ah + (size_t)rb * BL + k0 + qa, sAh + lb1);
        gload16(Al + (size_t)ra * BL + k0 + qa, sAl + lb0);
        gload16(Al + (size_t)rb * BL + k0 + qa, sAl + lb1);
        gload16(Bh + (size_t)ra * BL + k0 + qa, sBh + lb0);
        gload16(Bh + (size_t)rb * BL + k0 + qa, sBh + lb1);
        gload16(Bl + (size_t)ra * BL + k0 + qa, sBl + lb0);
        gload16(Bl + (size_t)rb * BL + k0 + qa, sBl + lb1);
        __syncthreads();   // DMA drained
        bf16x8 ah[4], al[4], bh[4], bl[4];
#pragma unroll
        for (int r = 0; r < 4; ++r) {
            ah[r] = *(const bf16x8*)&sAh[(wr + r * 16 + lrow) * 32 + lq];
            al[r] = *(const bf16x8*)&sAl[(wr + r * 16 + lrow) * 32 + lq];
        }
#pragma unroll
        for (int c = 0; c < 4; ++c) {
            bh[c] = *(const bf16x8*)&sBh[(wc + c * 16 + lrow) * 32 + lq];
            bl[c] = *(const bf16x8*)&sBl[(wc + c * 16 + lrow) * 32 + lq];
        }
#pragma unroll
        for (int r = 0; r < 4; ++r)
#pragma unroll
            for (int c = 0; c < 4; ++c) {
                acc[r][c] = __builtin_amdgcn_mfma_f32_16x16x32_bf16(ah[r], bh[c], acc[r][c], 0, 0, 0);
                acc[r][c] = __builtin_amdgcn_mfma_f32_16x16x32_bf16(ah[r], bl[c], acc[r][c], 0, 0, 0);
                acc[r][c] = __builtin_amdgcn_mfma_f32_16x16x32_bf16(al[r], bh[c], acc[r][c], 0, 0, 0);
            }
    }
    float* P = part + (size_t)z * PART_STRIDE + (size_t)blockIdx.x * 16384;
    const int orow = wr + (l >> 4) * 4;      // in-tile row
    const int ocol = wc + lrow;              // in-tile col
#pragma unroll
    for (int r = 0; r < 4; ++r)
#pragma unroll
        for (int c = 0; c < 4; ++c)
#pragma unroll
            for (int p = 0; p < 4; ++p)
                P[(size_t)(orow + r * 16 + p) * 128 + ocol + c * 16] = acc[r][c][p];
}

// ---------------------------------------------------------------------------
// Reduce partials -> sim (both triangles, scaled by 1/B). Grid (36, 4):
// block = 64x64 quadrant of an upper-tri tile. Mirror via LDS transpose.
__global__ __launch_bounds__(256) void k_reduce(const float* __restrict__ part,
                                                float* __restrict__ sim) {
    __shared__ float tl[64][65];
    const int t = threadIdx.x;
    int id = blockIdx.x, ti = 0;
    while (id >= 8 - ti) { id -= 8 - ti; ++ti; }
    const int tj = ti + id;
    const int q = blockIdx.y;
    const int r0 = (q >> 1) * 64, c0 = (q & 1) * 64;
    const float* Pu = part + (size_t)blockIdx.x * 16384;
#pragma unroll
    for (int e = 0; e < 16; ++e) {
        int li = e * 256 + t;
        int r = li >> 6, c = li & 63;
        float s = 0.f;
#pragma unroll
        for (int z = 0; z < SPLITK; ++z)
            s += Pu[(size_t)z * PART_STRIDE + (size_t)(r0 + r) * 128 + c0 + c];
        tl[r][c] = s * (1.0f / BB);
    }
    __syncthreads();
#pragma unroll
    for (int e = 0; e < 16; ++e) {
        int li = e * 256 + t;
        int r = li >> 6, c = li & 63;
        sim[(size_t)(ti * 128 + r0 + r) * NN + tj * 128 + c0 + c] = tl[r][c];
    }
    if (ti != tj) {
#pragma unroll
        for (int e = 0; e < 16; ++e) {
            int li = e * 256 + t;
            int cc = li >> 6, rr = li & 63;   // rr consecutive -> coalesced
            sim[(size_t)(tj * 128 + c0 + cc) * NN + ti * 128 + r0 + rr] = tl[rr][cc];
        }
    }
}

// ---------------------------------------------------------------------------
// K3: exact top-307 per row (excl self), one wave/row, ballot binary search.
// Fused: atomicAdd kept weights into deg[dst] (deg pre-zeroed).
__global__ __launch_bounds__(256) void k_topk(const float* __restrict__ sim,
                                              float* __restrict__ A,
                                              float* __restrict__ deg) {
    const int t = threadIdx.x, l = t & 63, w = t >> 6;
    const int n = blockIdx.x * 4 + w;
    const float* row = sim + (size_t)n * NN;
    float v[16]; unsigned key[16];
#pragma unroll
    for (int j = 0; j < 16; ++j) {
        int m = j * 64 + l;
        float f = row[m];
        v[j] = f;
        unsigned u = __float_as_uint(f);
        unsigned kk = (u & 0x80000000u) ? ~u : (u | 0x80000000u);
        key[j] = (m == n) ? 0u : kk;   // self excluded (self-sim is row max)
    }
    unsigned cur = 0u;
    for (int bit = 31; bit >= 0; --bit) {
        unsigned cand = cur | (1u << bit);
        int c = 0;
#pragma unroll
        for (int j = 0; j < 16; ++j)
            c += __popcll(__ballot(key[j] >= cand));
        if (c >= TOPK) cur = cand;
    }
    const unsigned T = cur;
    int cgt = 0; u64 eq[16];
#pragma unroll
    for (int j = 0; j < 16; ++j) {
        cgt += __popcll(__ballot(key[j] > T));
        eq[j] = __ballot(key[j] == T);
    }
    const int need = TOPK - cgt;
    const u64 mymask = (l == 0) ? 0ull : (~0ull >> (64 - l));
    int base = 0;
#pragma unroll
    for (int j = 0; j < 16; ++j) {
        int rank = base + __popcll(eq[j] & mymask);
        bool keep = (key[j] > T) | ((key[j] == T) & (rank < need));
        float av = keep ? v[j] : 0.0f;
        A[(size_t)n * NN + j * 64 + l] = av;
        if (keep) atomicAdd(&deg[j * 64 + l], av);
        base += __popcll(eq[j]);
    }
}

// ---------------------------------------------------------------------------
// K5: Atr[d][s] = bf16( A[s][d] * dinv(deg[d]) * dinv(deg[s]) )  (dinv inline)
__global__ __launch_bounds__(256) void k_prescale_tr(const float* __restrict__ A,
                                                     const float* __restrict__ deg,
                                                     ushort_t* __restrict__ Atr) {
    __shared__ float tile[32][33];
    int c0 = blockIdx.x * 32;   // d
    int r0 = blockIdx.y * 32;   // s
    int tx = threadIdx.x, ty = threadIdx.y;
#pragma unroll
    for (int j = 0; j < 32; j += 8)
        tile[ty + j][tx] = A[(size_t)(r0 + ty + j) * NN + c0 + tx];
    __syncthreads();
#pragma unroll
    for (int j = 0; j < 32; j += 8) {
        int d = c0 + ty + j;
        int s = r0 + tx;
        float dd = deg[d], ds_ = deg[s];
        float di = (dd > 0.f) ? (1.0f / sqrtf(dd)) : 0.0f;
        float si = (ds_ > 0.f) ? (1.0f / sqrtf(ds_)) : 0.0f;
        Atr[(size_t)d * NN + s] = f2bf(tile[tx][ty + j] * di * si);
    }
}

// ---------------------------------------------------------------------------
// K5b: WT[o][l] = bf16( W[l][o] )
__global__ __launch_bounds__(256) void k_wt(const float* __restrict__ W,
                                            ushort_t* __restrict__ WT) {
    __shared__ float tile[32][33];
    int c0 = blockIdx.x * 32;   // o
    int r0 = blockIdx.y * 32;   // l
    int tx = threadIdx.x, ty = threadIdx.y;
#pragma unroll
    for (int j = 0; j < 32; j += 8)
        tile[ty + j][tx] = W[(size_t)(r0 + ty + j) * LL + c0 + tx];
    __syncthreads();
#pragma unroll
    for (int j = 0; j < 32; j += 8)
        WT[(size_t)(c0 + ty + j) * LL + r0 + tx] = f2bf(tile[tx][ty + j]);
}

// ---------------------------------------------------------------------------
// Generic bf16 NT MFMA GEMM: C[i][j] = sum_k A[i][k]*B[j][k] (+bias for fp32).
// 128x128 tile, BK=32, 2x2 waves acc[4][4], LDS double-buffer (32KB) +
// global_load_lds, batched via blockIdx.z.
__global__ __launch_bounds__(256, 4) void k_mfma_nt(const ushort_t* __restrict__ A,
                                                    const ushort_t* __restrict__ B,
                                                    void* __restrict__ Cv,
                                                    const float* __restrict__ bias,
                                                    int lda, int ldb, int ldc,
                                                    long strA, long strB, long strC,
                                                    int K, int bf16out) {
    __shared__ ushort_t sA[2][4096], sB[2][4096];
    const int t = threadIdx.x, l = t & 63, w = t >> 6;
    const int i0 = blockIdx.y * 128, j0 = blockIdx.x * 128, z = blockIdx.z;
    const ushort_t* Ab = A + (size_t)z * strA;
    const ushort_t* Bb = B + (size_t)z * strB;
    const int ra = t >> 2, qa = (t & 3) * 8;
    const int rb = ra + 64;
    const int lb0 = 512 * w, lb1 = 512 * (w + 4);
    const int wr = (w >> 1) * 64, wc = (w & 1) * 64;
    const int lrow = l & 15, lq = (l >> 4) * 8;

    auto dma = [&](int k0, int buf) {
        gload16(Ab + (size_t)(i0 + ra) * lda + k0 + qa, &sA[buf][lb0]);
        gload16(Ab + (size_t)(i0 + rb) * lda + k0 + qa, &sA[buf][lb1]);
        gload16(Bb + (size_t)(j0 + ra) * ldb + k0 + qa, &sB[buf][lb0]);
        gload16(Bb + (size_t)(j0 + rb) * ldb + k0 + qa, &sB[buf][lb1]);
    };

    f32x4 acc[4][4] = {};
    dma(0, 0);
    for (int k0 = 0; k0 < K; k0 += 32) {
        const int cur = (k0 >> 5) & 1;
        __syncthreads();                        // drains DMA into buf[cur]
        if (k0 + 32 < K) dma(k0 + 32, cur ^ 1); // prefetch next into other buf
        bf16x8 af[4], bf_[4];
#pragma unroll
        for (int r = 0; r < 4; ++r)
            af[r] = *(const bf16x8*)&sA[cur][(wr + r * 16 + lrow) * 32 + lq];
#pragma unroll
        for (int c = 0; c < 4; ++c)
            bf_[c] = *(const bf16x8*)&sB[cur][(wc + c * 16 + lrow) * 32 + lq];
#pragma unroll
        for (int r = 0; r < 4; ++r)
#pragma unroll
            for (int c = 0; c < 4; ++c)
                acc[r][c] = __builtin_amdgcn_mfma_f32_16x16x32_bf16(af[r], bf_[c], acc[r][c], 0, 0, 0);
    }
    const int orow = i0 + wr + (l >> 4) * 4;
    const int ocol = j0 + wc + lrow;
    if (bf16out) {
        ushort_t* Cp = (ushort_t*)Cv + (size_t)z * strC;
#pragma unroll
        for (int r = 0; r < 4; ++r)
#pragma unroll
            for (int c = 0; c < 4; ++c)
#pragma unroll
                for (int p = 0; p < 4; ++p)
                    Cp[(size_t)(orow + r * 16 + p) * ldc + ocol + c * 16] = f2bf(acc[r][c][p]);
    } else {
        float* Cp = (float*)Cv + (size_t)z * strC;
#pragma unroll
        for (int r = 0; r < 4; ++r)
#pragma unroll
            for (int c = 0; c < 4; ++c)
#pragma unroll
                for (int p = 0; p < 4; ++p) {
                    float bv = bias ? bias[(orow + r * 16 + p) & (LL - 1)] : 0.0f;
                    Cp[(size_t)(orow + r * 16 + p) * ldc + ocol + c * 16] = acc[r][c][p] + bv;
                }
    }
}

// ---------------------------------------------------------------------------
extern "C" void kernel_launch(void* const* d_in, const int* in_sizes, int n_in,
                              void* d_out, int out_size, void* d_ws, size_t ws_size,
                              hipStream_t stream) {
    const float* x      = (const float*)d_in[0];   // [B, L, N]
    const float* weight = (const float*)d_in[1];   // [L, L]
    const float* bias   = (const float*)d_in[2];   // [L]
    float* out = (float*)d_out;                    // [B, L, N] == [bl][d]

    char* p = (char*)d_ws;
    ushort_t* xhi  = (ushort_t*)p; p += (size_t)NN * BL * 2;          // 16.8MB
    ushort_t* xlo  = (ushort_t*)p; p += (size_t)NN * BL * 2;          // 16.8MB
    ushort_t* xbf  = (ushort_t*)p; p += (size_t)NN * BL * 2;          // 16.8MB
    float*    part = (float*)p;                                        // 37.75MB
    ushort_t* xwT  = (ushort_t*)p;                                     // aliases part (16.8MB; part dead before GEMM2)
    p += (size_t)SPLITK * PART_STRIDE * 4;
    ushort_t* Atrb = (ushort_t*)p; p += (size_t)NN * NN * 2;          // 2.1MB
    ushort_t* WTb  = (ushort_t*)p; p += (size_t)LL * LL * 2;          // 128KB
    float* sim  = (float*)p; p += (size_t)NN * NN * 4;                // 4.2MB
    float* Aw   = (float*)p; p += (size_t)NN * NN * 4;                // 4.2MB
    float* deg  = (float*)p; p += NN * 4;

    // 1. fused: norms + transpose to node-major bf16 (hi/lo normalized + raw)
    k_prep<<<dim3(NN / 32, BB), dim3(32, 8), 0, stream>>>(x, xhi, xlo, xbf);
    hipMemsetAsync(deg, 0, NN * 4, stream);
    // 2. sim partials (split-bf16 MFMA, upper-tri tiles, splitK=16, no atomics)
    k_sim_mfma<<<dim3(NTILES, SPLITK), 256, 0, stream>>>(xhi, xlo, part);
    // 3. reduce partials -> full sim (mirror fused, 1/B scale)
    k_reduce<<<dim3(NTILES, 4), 256, 0, stream>>>(part, sim);
    // 4. exact top-307 per row -> Aw, fused deg accumulation
    k_topk<<<dim3(NN / 4), 256, 0, stream>>>(sim, Aw, deg);
    // 5. Atr = bf16(D^-1/2 A^T D^-1/2) with inline rsqrt; WT = bf16(W^T)
    k_wt<<<dim3(LL / 32, LL / 32), dim3(32, 8), 0, stream>>>(weight, WTb);
    k_prescale_tr<<<dim3(NN / 32, NN / 32), dim3(32, 8), 0, stream>>>(Aw, deg, Atrb);
    // 6. xwT[b*256+o][n] = sum_l WT[o][l] * xbf[n][b*256+l]  (batched NT, bf16 out)
    k_mfma_nt<<<dim3(NN / 128, LL / 128, BB), 256, 0, stream>>>(
        WTb, xbf, xwT, nullptr, LL, BL, NN, 0, LL, (long)LL * NN, LL, 1);
    // 7. out[bl][d] = sum_s xwT[bl][s] * Atr[d][s] + bias[bl&255]  (NT, fused epilogue)
    k_mfma_nt<<<dim3(NN / 128, BL / 128, 1), 256, 0, stream>>>(
        xwT, Atrb, out, bias, NN, NN, NN, 0, 0, 0, NN, 0);
}

// Round 7
// 247.343 us; speedup vs baseline: 1.1901x; 1.0101x over previous
//
#include <hip/hip_runtime.h>

// Problem constants
#define BB 32
#define LL 256
#define NN 1024
#define BL 8192         // B*L
#define TOPK 307        // int(1024*0.3)
#define SPLITK 16
#define NTILES 36       // upper-tri 128x128 tiles of 1024x1024
#define PART_STRIDE ((size_t)NTILES * 16384)

typedef unsigned short ushort_t;
typedef unsigned long long u64;
typedef __bf16 bf16x8 __attribute__((ext_vector_type(8)));
typedef float f32x4 __attribute__((ext_vector_type(4)));

// round-to-nearest-even float -> bf16
__device__ __forceinline__ ushort_t f2bf(float f) {
    unsigned int u = __float_as_uint(f);
    u += 0x7FFFu + ((u >> 16) & 1u);
    return (ushort_t)(u >> 16);
}
__device__ __forceinline__ float bf2f(ushort_t h) {
    return __uint_as_float(((unsigned int)h) << 16);
}

// async global->LDS DMA, 16B/lane; LDS dest = wave-uniform base + lane*16
__device__ __forceinline__ void gload16(const void* g, const void* l) {
    __builtin_amdgcn_global_load_lds(
        (__attribute__((address_space(1))) void*)(unsigned long long)g,
        (__attribute__((address_space(3))) void*)(unsigned int)(unsigned long long)l,
        16, 0, 0);
}

// LDS bank-conflict swizzle: LDS (row, quad-slot qp) holds global k-quad
// g = (qp - (row>>1)) & 3. Writer thread t (row=t>>2, qp=t&3) sources quad
// ((t&3) - ((t>>2)>>1)) & 3; rows +64 give the same value (32 ≡ 0 mod 4).
// Reader: slot for quad g of row r is (g + (r>>1)) & 3 -> 2-way banks (free).

// ---------------------------------------------------------------------------
// K1 (fused norms + transpose): one pass over x. Emits node-major bf16 xhi/xlo
// (normalized hi/lo split) and fp32 nrm[b][n] (clamped L2 norm).
__global__ __launch_bounds__(256) void k_prep(const float* __restrict__ x,
                                              ushort_t* __restrict__ xhi,
                                              ushort_t* __restrict__ xlo,
                                              float* __restrict__ nrm) {
    __shared__ float tile[LL][33];
    __shared__ float red[8][33];
    __shared__ float inv[32];
    const int tx = threadIdx.x, ty = threadIdx.y;
    const int n0 = blockIdx.x * 32, b = blockIdx.y;
    const float* xb = x + (size_t)b * LL * NN + n0;
    float s = 0.f;
#pragma unroll
    for (int j = 0; j < 32; ++j) {
        int l = j * 8 + ty;
        float v = xb[(size_t)l * NN + tx];
        tile[l][tx] = v;
        s = fmaf(v, v, s);
    }
    red[ty][tx] = s;
    __syncthreads();
    if (ty == 0) {
        float acc = 0.f;
#pragma unroll
        for (int j = 0; j < 8; ++j) acc += red[j][tx];
        float nv = fmaxf(sqrtf(acc), 1e-12f);
        nrm[b * NN + n0 + tx] = nv;
        inv[tx] = 1.0f / nv;
    }
    __syncthreads();
    const int tid = ty * 32 + tx;   // == l for the write phase
#pragma unroll
    for (int nl = 0; nl < 32; ++nl) {
        float v = tile[tid][nl];
        size_t o = (size_t)(n0 + nl) * BL + b * LL + tid;
        float sc = v * inv[nl];
        ushort_t hi = f2bf(sc);
        xhi[o] = hi;
        xlo[o] = f2bf(sc - bf2f(hi));
    }
}

// ---------------------------------------------------------------------------
// GEMM1: partial sims, split-bf16 (hi*hi + hi*lo + lo*hi), MFMA.
// Upper-tri 128-tiles, splitK=16, no atomics, swizzled LDS (conflict-free).
__global__ __launch_bounds__(256, 4) void k_sim_mfma(const ushort_t* __restrict__ Xhi,
                                                     const ushort_t* __restrict__ Xlo,
                                                     float* __restrict__ part) {
    __shared__ ushort_t sAh[4096], sAl[4096];
    __shared__ ushort_t sBh[4096], sBl[4096];
    const int t = threadIdx.x, l = t & 63, w = t >> 6;
    int id = blockIdx.x, ti = 0;               // [0,36) -> upper-tri (ti,tj)
    while (id >= 8 - ti) { id -= 8 - ti; ++ti; }
    const int tj = ti + id;
    const int i0 = ti * 128, j0 = tj * 128;
    const int z = blockIdx.y;
    const int it0 = 16 * z, it1 = it0 + 16;
    const int ra = t >> 2;
    const int rb = ra + 64;
    const int qa = ((((t & 3) - (ra >> 1)) & 3)) * 8;   // swizzled source quad
    const int lb0 = 512 * w, lb1 = 512 * (w + 4);
    const int wr = (w >> 1) * 64, wc = (w & 1) * 64;
    const int lrow = l & 15, g = l >> 4;
    const ushort_t* Ah = Xhi + (size_t)i0 * BL;
    const ushort_t* Al = Xlo + (size_t)i0 * BL;
    const ushort_t* Bh = Xhi + (size_t)j0 * BL;
    const ushort_t* Bl = Xlo + (size_t)j0 * BL;

    // hoisted swizzled fragment offsets
    int offA[4], offB[4];
#pragma unroll
    for (int r = 0; r < 4; ++r) {
        int row = wr + r * 16 + lrow;
        offA[r] = row * 32 + (((g + (row >> 1)) & 3) * 8);
        row = wc + r * 16 + lrow;
        offB[r] = row * 32 + (((g + (row >> 1)) & 3) * 8);
    }

    f32x4 acc[4][4] = {};
    for (int it = it0; it < it1; ++it) {
        const int k0 = it * 32;
        __syncthreads();   // prior iter's LDS reads done
        gload16(Ah + (size_t)ra * BL + k0 + qa, sAh + lb0);
        gload16(Ah + (size_t)rb * BL + k0 + qa, sAh + lb1);
        gload16(Al + (size_t)ra * BL + k0 + qa, sAl + lb0);
        gload16(Al + (size_t)rb * BL + k0 + qa, sAl + lb1);
        gload16(Bh + (size_t)ra * BL + k0 + qa, sBh + lb0);
        gload16(Bh + (size_t)rb * BL + k0 + qa, sBh + lb1);
        gload16(Bl + (size_t)ra * BL + k0 + qa, sBl + lb0);
        gload16(Bl + (size_t)rb * BL + k0 + qa, sBl + lb1);
        __syncthreads();   // DMA drained
        bf16x8 ah[4], al[4], bh[4], bl[4];
#pragma unroll
        for (int r = 0; r < 4; ++r) {
            ah[r] = *(const bf16x8*)&sAh[offA[r]];
            al[r] = *(const bf16x8*)&sAl[offA[r]];
        }
#pragma unroll
        for (int c = 0; c < 4; ++c) {
            bh[c] = *(const bf16x8*)&sBh[offB[c]];
            bl[c] = *(const bf16x8*)&sBl[offB[c]];
        }
#pragma unroll
        for (int r = 0; r < 4; ++r)
#pragma unroll
            for (int c = 0; c < 4; ++c) {
                acc[r][c] = __builtin_amdgcn_mfma_f32_16x16x32_bf16(ah[r], bh[c], acc[r][c], 0, 0, 0);
                acc[r][c] = __builtin_amdgcn_mfma_f32_16x16x32_bf16(ah[r], bl[c], acc[r][c], 0, 0, 0);
                acc[r][c] = __builtin_amdgcn_mfma_f32_16x16x32_bf16(al[r], bh[c], acc[r][c], 0, 0, 0);
            }
    }
    float* P = part + (size_t)z * PART_STRIDE + (size_t)blockIdx.x * 16384;
    const int orow = wr + (l >> 4) * 4;
    const int ocol = wc + lrow;
#pragma unroll
    for (int r = 0; r < 4; ++r)
#pragma unroll
        for (int c = 0; c < 4; ++c)
#pragma unroll
            for (int p = 0; p < 4; ++p)
                P[(size_t)(orow + r * 16 + p) * 128 + ocol + c * 16] = acc[r][c][p];
}

// ---------------------------------------------------------------------------
// Reduce partials -> sim (both triangles, scaled by 1/B).
__global__ __launch_bounds__(256) void k_reduce(const float* __restrict__ part,
                                                float* __restrict__ sim) {
    __shared__ float tl[64][65];
    const int t = threadIdx.x;
    int id = blockIdx.x, ti = 0;
    while (id >= 8 - ti) { id -= 8 - ti; ++ti; }
    const int tj = ti + id;
    const int q = blockIdx.y;
    const int r0 = (q >> 1) * 64, c0 = (q & 1) * 64;
    const float* Pu = part + (size_t)blockIdx.x * 16384;
#pragma unroll
    for (int e = 0; e < 16; ++e) {
        int li = e * 256 + t;
        int r = li >> 6, c = li & 63;
        float s = 0.f;
#pragma unroll
        for (int z = 0; z < SPLITK; ++z)
            s += Pu[(size_t)z * PART_STRIDE + (size_t)(r0 + r) * 128 + c0 + c];
        tl[r][c] = s * (1.0f / BB);
    }
    __syncthreads();
#pragma unroll
    for (int e = 0; e < 16; ++e) {
        int li = e * 256 + t;
        int r = li >> 6, c = li & 63;
        sim[(size_t)(ti * 128 + r0 + r) * NN + tj * 128 + c0 + c] = tl[r][c];
    }
    if (ti != tj) {
#pragma unroll
        for (int e = 0; e < 16; ++e) {
            int li = e * 256 + t;
            int cc = li >> 6, rr = li & 63;   // rr consecutive -> coalesced
            sim[(size_t)(tj * 128 + c0 + cc) * NN + ti * 128 + r0 + rr] = tl[rr][cc];
        }
    }
}

// ---------------------------------------------------------------------------
// K3: exact top-307 per row (excl self), one wave/row, ballot binary search.
// Fused: atomicAdd kept weights into deg[dst] (deg pre-zeroed).
__global__ __launch_bounds__(256) void k_topk(const float* __restrict__ sim,
                                              float* __restrict__ A,
                                              float* __restrict__ deg) {
    const int t = threadIdx.x, l = t & 63, w = t >> 6;
    const int n = blockIdx.x * 4 + w;
    const float* row = sim + (size_t)n * NN;
    float v[16]; unsigned key[16];
#pragma unroll
    for (int j = 0; j < 16; ++j) {
        int m = j * 64 + l;
        float f = row[m];
        v[j] = f;
        unsigned u = __float_as_uint(f);
        unsigned kk = (u & 0x80000000u) ? ~u : (u | 0x80000000u);
        key[j] = (m == n) ? 0u : kk;   // self excluded (self-sim is row max)
    }
    unsigned cur = 0u;
    for (int bit = 31; bit >= 0; --bit) {
        unsigned cand = cur | (1u << bit);
        int c = 0;
#pragma unroll
        for (int j = 0; j < 16; ++j)
            c += __popcll(__ballot(key[j] >= cand));
        if (c >= TOPK) cur = cand;
    }
    const unsigned T = cur;
    int cgt = 0; u64 eq[16];
#pragma unroll
    for (int j = 0; j < 16; ++j) {
        cgt += __popcll(__ballot(key[j] > T));
        eq[j] = __ballot(key[j] == T);
    }
    const int need = TOPK - cgt;
    const u64 mymask = (l == 0) ? 0ull : (~0ull >> (64 - l));
    int base = 0;
#pragma unroll
    for (int j = 0; j < 16; ++j) {
        int rank = base + __popcll(eq[j] & mymask);
        bool keep = (key[j] > T) | ((key[j] == T) & (rank < need));
        float av = keep ? v[j] : 0.0f;
        A[(size_t)n * NN + j * 64 + l] = av;
        if (keep) atomicAdd(&deg[j * 64 + l], av);
        base += __popcll(eq[j]);
    }
}

// ---------------------------------------------------------------------------
// K5: Atr[d][s] = bf16( A[s][d] * dinv(deg[d]) * dinv(deg[s]) )  (dinv inline)
__global__ __launch_bounds__(256) void k_prescale_tr(const float* __restrict__ A,
                                                     const float* __restrict__ deg,
                                                     ushort_t* __restrict__ Atr) {
    __shared__ float tile[32][33];
    int c0 = blockIdx.x * 32;   // d
    int r0 = blockIdx.y * 32;   // s
    int tx = threadIdx.x, ty = threadIdx.y;
#pragma unroll
    for (int j = 0; j < 32; j += 8)
        tile[ty + j][tx] = A[(size_t)(r0 + ty + j) * NN + c0 + tx];
    __syncthreads();
#pragma unroll
    for (int j = 0; j < 32; j += 8) {
        int d = c0 + ty + j;
        int s = r0 + tx;
        float dd = deg[d], ds_ = deg[s];
        float di = (dd > 0.f) ? (1.0f / sqrtf(dd)) : 0.0f;
        float si = (ds_ > 0.f) ? (1.0f / sqrtf(ds_)) : 0.0f;
        Atr[(size_t)d * NN + s] = f2bf(tile[tx][ty + j] * di * si);
    }
}

// ---------------------------------------------------------------------------
// K5b: WT[o][l] = bf16( W[l][o] )
__global__ __launch_bounds__(256) void k_wt(const float* __restrict__ W,
                                            ushort_t* __restrict__ WT) {
    __shared__ float tile[32][33];
    int c0 = blockIdx.x * 32;   // o
    int r0 = blockIdx.y * 32;   // l
    int tx = threadIdx.x, ty = threadIdx.y;
#pragma unroll
    for (int j = 0; j < 32; j += 8)
        tile[ty + j][tx] = W[(size_t)(r0 + ty + j) * LL + c0 + tx];
    __syncthreads();
#pragma unroll
    for (int j = 0; j < 32; j += 8)
        WT[(size_t)(c0 + ty + j) * LL + r0 + tx] = f2bf(tile[tx][ty + j]);
}

// ---------------------------------------------------------------------------
// Generic bf16 NT MFMA GEMM: C[i][j] = sum_k A[i][k]*B[j][k].
// 128x128 tile, BK=32, 2x2 waves acc[4][4], LDS dbuf + global_load_lds,
// swizzled LDS (conflict-free), batched via blockIdx.z.
// bf16out: optional per-column scale cscale[z*NN + col]; fp32 out: +bias[i&255].
__global__ __launch_bounds__(256, 4) void k_mfma_nt(const ushort_t* __restrict__ A,
                                                    const ushort_t* __restrict__ B,
                                                    void* __restrict__ Cv,
                                                    const float* __restrict__ bias,
                                                    const float* __restrict__ cscale,
                                                    int lda, int ldb, int ldc,
                                                    long strA, long strB, long strC,
                                                    int K, int bf16out) {
    __shared__ ushort_t sA[2][4096], sB[2][4096];
    const int t = threadIdx.x, l = t & 63, w = t >> 6;
    const int i0 = blockIdx.y * 128, j0 = blockIdx.x * 128, z = blockIdx.z;
    const ushort_t* Ab = A + (size_t)z * strA;
    const ushort_t* Bb = B + (size_t)z * strB;
    const int ra = t >> 2;
    const int rb = ra + 64;
    const int qa = ((((t & 3) - (ra >> 1)) & 3)) * 8;   // swizzled source quad
    const int lb0 = 512 * w, lb1 = 512 * (w + 4);
    const int wr = (w >> 1) * 64, wc = (w & 1) * 64;
    const int lrow = l & 15, g = l >> 4;

    int offA[4], offB[4];
#pragma unroll
    for (int r = 0; r < 4; ++r) {
        int row = wr + r * 16 + lrow;
        offA[r] = row * 32 + (((g + (row >> 1)) & 3) * 8);
        row = wc + r * 16 + lrow;
        offB[r] = row * 32 + (((g + (row >> 1)) & 3) * 8);
    }

    auto dma = [&](int k0, int buf) {
        gload16(Ab + (size_t)(i0 + ra) * lda + k0 + qa, &sA[buf][lb0]);
        gload16(Ab + (size_t)(i0 + rb) * lda + k0 + qa, &sA[buf][lb1]);
        gload16(Bb + (size_t)(j0 + ra) * ldb + k0 + qa, &sB[buf][lb0]);
        gload16(Bb + (size_t)(j0 + rb) * ldb + k0 + qa, &sB[buf][lb1]);
    };

    f32x4 acc[4][4] = {};
    dma(0, 0);
    for (int k0 = 0; k0 < K; k0 += 32) {
        const int cur = (k0 >> 5) & 1;
        __syncthreads();                        // drains DMA into buf[cur]
        if (k0 + 32 < K) dma(k0 + 32, cur ^ 1); // prefetch next into other buf
        bf16x8 af[4], bf_[4];
#pragma unroll
        for (int r = 0; r < 4; ++r)
            af[r] = *(const bf16x8*)&sA[cur][offA[r]];
#pragma unroll
        for (int c = 0; c < 4; ++c)
            bf_[c] = *(const bf16x8*)&sB[cur][offB[c]];
#pragma unroll
        for (int r = 0; r < 4; ++r)
#pragma unroll
            for (int c = 0; c < 4; ++c)
                acc[r][c] = __builtin_amdgcn_mfma_f32_16x16x32_bf16(af[r], bf_[c], acc[r][c], 0, 0, 0);
    }
    const int orow = i0 + wr + (l >> 4) * 4;
    const int ocol = j0 + wc + lrow;
    if (bf16out) {
        ushort_t* Cp = (ushort_t*)Cv + (size_t)z * strC;
#pragma unroll
        for (int c = 0; c < 4; ++c) {
            float sc = cscale ? cscale[(size_t)z * NN + ocol + c * 16] : 1.0f;
#pragma unroll
            for (int r = 0; r < 4; ++r)
#pragma unroll
                for (int p = 0; p < 4; ++p)
                    Cp[(size_t)(orow + r * 16 + p) * ldc + ocol + c * 16] = f2bf(acc[r][c][p] * sc);
        }
    } else {
        float* Cp = (float*)Cv + (size_t)z * strC;
#pragma unroll
        for (int r = 0; r < 4; ++r)
#pragma unroll
            for (int c = 0; c < 4; ++c)
#pragma unroll
                for (int p = 0; p < 4; ++p) {
                    float bv = bias ? bias[(orow + r * 16 + p) & (LL - 1)] : 0.0f;
                    Cp[(size_t)(orow + r * 16 + p) * ldc + ocol + c * 16] = acc[r][c][p] + bv;
                }
    }
}

// ---------------------------------------------------------------------------
extern "C" void kernel_launch(void* const* d_in, const int* in_sizes, int n_in,
                              void* d_out, int out_size, void* d_ws, size_t ws_size,
                              hipStream_t stream) {
    const float* x      = (const float*)d_in[0];   // [B, L, N]
    const float* weight = (const float*)d_in[1];   // [L, L]
    const float* bias   = (const float*)d_in[2];   // [L]
    float* out = (float*)d_out;                    // [B, L, N] == [bl][d]

    char* p = (char*)d_ws;
    ushort_t* xhi  = (ushort_t*)p; p += (size_t)NN * BL * 2;          // 16.8MB
    ushort_t* xlo  = (ushort_t*)p; p += (size_t)NN * BL * 2;          // 16.8MB
    float*    part = (float*)p;                                        // 37.75MB
    ushort_t* xwT  = (ushort_t*)p;                                     // aliases part (dead before GEMM2)
    p += (size_t)SPLITK * PART_STRIDE * 4;
    ushort_t* Atrb = (ushort_t*)p; p += (size_t)NN * NN * 2;          // 2.1MB
    ushort_t* WTb  = (ushort_t*)p; p += (size_t)LL * LL * 2;          // 128KB
    float* sim  = (float*)p; p += (size_t)NN * NN * 4;                // 4.2MB
    float* Aw   = (float*)p; p += (size_t)NN * NN * 4;                // 4.2MB
    float* deg  = (float*)p; p += NN * 4;
    float* nrm  = (float*)p; p += (size_t)BB * NN * 4;                // 128KB

    // 1. fused: norms + transpose to node-major bf16 hi/lo + fp32 norms
    k_prep<<<dim3(NN / 32, BB), dim3(32, 8), 0, stream>>>(x, xhi, xlo, nrm);
    hipMemsetAsync(deg, 0, NN * 4, stream);
    // 2. sim partials (split-bf16 MFMA, upper-tri tiles, splitK=16, no atomics)
    k_sim_mfma<<<dim3(NTILES, SPLITK), 256, 0, stream>>>(xhi, xlo, part);
    // 3. reduce partials -> full sim (mirror fused, 1/B scale)
    k_reduce<<<dim3(NTILES, 4), 256, 0, stream>>>(part, sim);
    // 4. exact top-307 per row -> Aw, fused deg accumulation
    k_topk<<<dim3(NN / 4), 256, 0, stream>>>(sim, Aw, deg);
    // 5. Atr = bf16(D^-1/2 A^T D^-1/2) with inline rsqrt; WT = bf16(W^T)
    k_wt<<<dim3(LL / 32, LL / 32), dim3(32, 8), 0, stream>>>(weight, WTb);
    k_prescale_tr<<<dim3(NN / 32, NN / 32), dim3(32, 8), 0, stream>>>(Aw, deg, Atrb);
    // 6. xwT[b*256+o][n] = nrm[b][n] * sum_l WT[o][l] * xhi[n][b*256+l]  (bf16 out)
    k_mfma_nt<<<dim3(NN / 128, LL / 128, BB), 256, 0, stream>>>(
        WTb, xhi, xwT, nullptr, nrm, LL, BL, NN, 0, LL, (long)LL * NN, LL, 1);
    // 7. out[bl][d] = sum_s xwT[bl][s] * Atr[d][s] + bias[bl&255]  (fp32 out)
    k_mfma_nt<<<dim3(NN / 128, BL / 128, 1), 256, 0, stream>>>(
        xwT, Atrb, out, bias, nullptr, NN, NN, NN, 0, 0, 0, NN, 0);
}